// Round 2
// baseline (176.252 us; speedup 1.0000x reference)
//
#include <hip/hip_runtime.h>
#include <hip/hip_bf16.h>

#define S_ 1024
#define D_ 64
#define QBLK 32
#define THREADS 256

typedef __attribute__((ext_vector_type(8)))  short short8;
typedef __attribute__((ext_vector_type(4)))  int   int4v;
typedef __attribute__((ext_vector_type(16))) float f32x16;
typedef __attribute__((ext_vector_type(4)))  float f32x4;

__device__ __forceinline__ unsigned short f2bfu(float x) {
  return __builtin_bit_cast(unsigned short, __float2bfloat16(x));
}
__device__ __forceinline__ float bfu2f(unsigned short s) {
  return __builtin_bit_cast(float, (unsigned)s << 16);
}

// ---------------------------------------------------------------------------
// Prep: qb = bf16(q * factor/8)  [bh][s][d]
//       kb = bf16(k)             [bh][s][d]
//       vp = bf16 V, transposed + MFMA-k-permuted: vp[bh][d][C*16+hi*8+i]
//            = V[bh][C*16+(i&3)+8*(i>>2)+4*hi][d]
//       mw = bit-packed mask: mw[b][s][w] bit j = mask[b][s][w*32+j]
// ---------------------------------------------------------------------------
__global__ __launch_bounds__(THREADS) void prep(
    const float* __restrict__ q, const float* __restrict__ k,
    const float* __restrict__ v, const float* __restrict__ factor,
    const int* __restrict__ mask, short* __restrict__ qb,
    short* __restrict__ kb, short* __restrict__ vp,
    unsigned* __restrict__ mw) {
  const int gid = blockIdx.x * THREADS + threadIdx.x;
  if (gid < 524288) {                       // qb: 8 elems/thread
    const int row = gid >> 3;               // bh*S + s
    const int c8 = (gid & 7) << 3;
    const float fs = factor[row] * 0.125f;
    const float* src = q + (((size_t)row) << 6) + c8;
    f32x4 x0 = *(const f32x4*)src;
    f32x4 x1 = *(const f32x4*)(src + 4);
    short8 o;
#pragma unroll
    for (int i = 0; i < 4; ++i) {
      o[i] = (short)f2bfu(x0[i] * fs);
      o[i + 4] = (short)f2bfu(x1[i] * fs);
    }
    *(short8*)(qb + (((size_t)row) << 6) + c8) = o;
  } else if (gid < 1048576) {               // kb
    const int g = gid - 524288;
    const int row = g >> 3;
    const int c8 = (g & 7) << 3;
    const float* src = k + (((size_t)row) << 6) + c8;
    f32x4 x0 = *(const f32x4*)src;
    f32x4 x1 = *(const f32x4*)(src + 4);
    short8 o;
#pragma unroll
    for (int i = 0; i < 4; ++i) {
      o[i] = (short)f2bfu(x0[i]);
      o[i + 4] = (short)f2bfu(x1[i]);
    }
    *(short8*)(kb + (((size_t)row) << 6) + c8) = o;
  } else if (gid < 1310720) {               // vp: one 16-key chunk per thread
    const int g = gid - 1048576;
    const int C = g & 63;
    const int d = (g >> 6) & 63;
    const int bh = g >> 12;
    const float* vsrc = v + (((size_t)bh) << 16) + d;
    short8 o0, o1;
#pragma unroll
    for (int i = 0; i < 8; ++i) {
      const int k0 = (C << 4) + (i & 3) + ((i >> 2) << 3);
      o0[i] = (short)f2bfu(vsrc[(size_t)k0 << 6]);        // hi = 0
      o1[i] = (short)f2bfu(vsrc[(size_t)(k0 + 4) << 6]);  // hi = 1
    }
    short* dst = vp + (((size_t)bh) << 16) + (((size_t)d) << 10) + (C << 4);
    *(short8*)dst = o0;
    *(short8*)(dst + 8) = o1;
  } else if (gid < 1441792) {               // mw: one u32 word per thread
    const int g = gid - 1310720;            // (b*S + s)*32 + w
    const int* msrc = mask + (((size_t)g) << 5);
    unsigned w = 0;
#pragma unroll
    for (int j = 0; j < 32; ++j) w |= (msrc[j] ? 1u : 0u) << j;
    mw[g] = w;
  }
}

// ---------------------------------------------------------------------------
// Main: block = (bh, 32 q-rows), 4 waves split K-tiles (strided).
// Pass 1: S^T = mfma(K,Q) (lane = q-col) -> mask -> exp -> psum + PV MFMAs
//         with P lane-local as A-operand (Vp gives contiguous B-frags).
// Then rowsums -> inv_l -> O cross-wave reduce -> store O.
// Pass 2: recompute S = mfma(Q,K) (lane = key-col), write normalized attn
//         straight from registers, coalesced.
// ---------------------------------------------------------------------------
__global__ __launch_bounds__(THREADS, 4) void attn_main(
    const short* __restrict__ qb, const short* __restrict__ kb,
    const short* __restrict__ vp, const unsigned* __restrict__ mw,
    float* __restrict__ out_o, float* __restrict__ out_attn) {
  __shared__ float o_part[4][QBLK][D_];   // 32 KB
  __shared__ float rs[4][QBLK];
  __shared__ float inv_l[QBLK];

  const int tid = threadIdx.x;
  const int wave = tid >> 6;
  const int lane = tid & 63;
  const int hi = lane >> 5;
  const int ln = lane & 31;

  const int qt = blockIdx.x & 31;
  const int bh = blockIdx.x >> 5;
  const int b  = bh >> 4;
  const int q0 = qt * QBLK;

  const short* qp = qb + (((size_t)bh * S_ + q0) << 6);
  const short* kp = kb + ((size_t)bh << 16);
  const short* vpp = vp + ((size_t)bh << 16);
  const unsigned* mwb = mw + ((size_t)b << 15);

  short8 qf[4];
#pragma unroll
  for (int kc = 0; kc < 4; ++kc)
    qf[kc] = *(const short8*)(qp + (ln << 6) + (kc << 4) + (hi << 3));

  f32x16 oa0, oa1;
#pragma unroll
  for (int i = 0; i < 16; ++i) { oa0[i] = 0.f; oa1[i] = 0.f; }
  float psum = 0.f;

  // ---- pass 1: swapped QK^T + PV ----
  for (int t = wave; t < 32; t += 4) {
    const int kv0 = t << 5;
    short8 kf[4];
#pragma unroll
    for (int kc = 0; kc < 4; ++kc)
      kf[kc] = *(const short8*)(kp + ((size_t)(kv0 + ln) << 6) + (kc << 4) + (hi << 3));
    f32x16 sB;
#pragma unroll
    for (int i = 0; i < 16; ++i) sB[i] = 0.f;
#pragma unroll
    for (int kc = 0; kc < 4; ++kc)
      sB = __builtin_amdgcn_mfma_f32_32x32x16_bf16(kf[kc], qf[kc], sB, 0, 0, 0);
    // mask word for this lane's q-row, this 32-key window
    const unsigned wb = mwb[((q0 + ln) << 5) + t];
    int pk[8];
#pragma unroll
    for (int j = 0; j < 8; ++j) {
      const int r0 = 2 * j;
      const int k0 = (r0 & 3) + ((r0 >> 2) << 3) + (hi << 2);  // key offset
      const float p0 = ((wb >> k0) & 1u) ? __expf(sB[r0]) : 0.f;
      const float p1 = ((wb >> (k0 + 1)) & 1u) ? __expf(sB[r0 + 1]) : 0.f;
      psum += p0 + p1;
      pk[j] = (int)f2bfu(p0) | ((int)f2bfu(p1) << 16);
    }
    int4v lo4 = {pk[0], pk[1], pk[2], pk[3]};
    int4v hi4 = {pk[4], pk[5], pk[6], pk[7]};
    const short8 pa0 = __builtin_bit_cast(short8, lo4);   // keys [kv0, kv0+16)
    const short8 pa1 = __builtin_bit_cast(short8, hi4);   // keys [kv0+16, +32)
    // Vp B-fragments: 16B contiguous per lane
    const short* vr0 = vpp + ((size_t)ln << 10) + (t << 5) + (hi << 3);
    const short8 v00 = *(const short8*)(vr0);
    const short8 v01 = *(const short8*)(vr0 + 16);
    oa0 = __builtin_amdgcn_mfma_f32_32x32x16_bf16(pa0, v00, oa0, 0, 0, 0);
    oa0 = __builtin_amdgcn_mfma_f32_32x32x16_bf16(pa1, v01, oa0, 0, 0, 0);
    const short* vr1 = vr0 + (32 << 10);
    const short8 v10 = *(const short8*)(vr1);
    const short8 v11 = *(const short8*)(vr1 + 16);
    oa1 = __builtin_amdgcn_mfma_f32_32x32x16_bf16(pa0, v10, oa1, 0, 0, 0);
    oa1 = __builtin_amdgcn_mfma_f32_32x32x16_bf16(pa1, v11, oa1, 0, 0, 0);
  }

  // ---- row sums -> inv_l ----
  psum += __shfl_xor(psum, 32);
  if (lane < 32) rs[wave][ln] = psum;
  __syncthreads();
  if (tid < QBLK)
    inv_l[tid] = 1.0f / (rs[0][tid] + rs[1][tid] + rs[2][tid] + rs[3][tid]);
  __syncthreads();

  // ---- O cross-wave reduce + store ----
  f32x4 ilv[4];
#pragma unroll
  for (int g = 0; g < 4; ++g)
    ilv[g] = *(const f32x4*)&inv_l[(g << 3) + (hi << 2)];
#pragma unroll
  for (int r = 0; r < 16; ++r) {
    const int row = (r & 3) + ((r >> 2) << 3) + (hi << 2);
    o_part[wave][row][ln] = oa0[r];
    o_part[wave][row][ln + 32] = oa1[r];
  }
  __syncthreads();
  float* op = out_o + (((size_t)bh * S_ + q0) << 6);
#pragma unroll
  for (int it = 0; it < 8; ++it) {
    const int idx = it * THREADS + tid;
    const int row = idx >> 6;
    const float o = o_part[0][row][idx & 63] + o_part[1][row][idx & 63] +
                    o_part[2][row][idx & 63] + o_part[3][row][idx & 63];
    op[idx] = o * inv_l[row];
  }

  // ---- pass 2: normal-orientation QK^T, write normalized attn ----
  float* ap = out_attn + (((size_t)bh * S_ + q0) << 10);
  for (int t = wave; t < 32; t += 4) {
    const int kv0 = t << 5;
    short8 kf[4];
#pragma unroll
    for (int kc = 0; kc < 4; ++kc)
      kf[kc] = *(const short8*)(kp + ((size_t)(kv0 + ln) << 6) + (kc << 4) + (hi << 3));
    f32x16 sA;
#pragma unroll
    for (int i = 0; i < 16; ++i) sA[i] = 0.f;
#pragma unroll
    for (int kc = 0; kc < 4; ++kc)
      sA = __builtin_amdgcn_mfma_f32_32x32x16_bf16(qf[kc], kf[kc], sA, 0, 0, 0);
#pragma unroll
    for (int j = 0; j < 8; ++j) {
      const int r0 = 2 * j;
      const int row0 = (r0 & 3) + ((r0 >> 2) << 3) + (hi << 2);  // q offset
      const unsigned w0 = mwb[((q0 + row0) << 5) + t];
      const unsigned w1 = mwb[((q0 + row0 + 1) << 5) + t];
      const float il0 = ilv[r0 >> 2][r0 & 3];
      const float il1 = ilv[r0 >> 2][(r0 & 3) + 1];
      const float p0 = ((w0 >> ln) & 1u) ? __expf(sA[r0]) * il0 : 0.f;
      const float p1 = ((w1 >> ln) & 1u) ? __expf(sA[r0 + 1]) * il1 : 0.f;
      ap[((size_t)row0 << 10) + kv0 + ln] = p0;
      ap[((size_t)(row0 + 1) << 10) + kv0 + ln] = p1;
    }
  }
}

extern "C" void kernel_launch(void* const* d_in, const int* in_sizes, int n_in,
                              void* d_out, int out_size, void* d_ws, size_t ws_size,
                              hipStream_t stream) {
  (void)in_sizes; (void)n_in; (void)ws_size; (void)out_size;
  const float* q = (const float*)d_in[0];
  const float* k = (const float*)d_in[1];
  const float* v = (const float*)d_in[2];
  const float* f = (const float*)d_in[3];
  const int*   m = (const int*)d_in[4];
  float* out_o    = (float*)d_out;
  float* out_attn = out_o + (size_t)4 * 16 * 1024 * 64;

  short* qbuf = (short*)d_ws;              // 4194304 bf16 = 8 MB
  short* kbuf = qbuf + 4194304;            // 8 MB
  short* vbuf = kbuf + 4194304;            // 8 MB
  unsigned* mwbuf = (unsigned*)(vbuf + 4194304);  // 512 KB

  prep<<<5632, THREADS, 0, stream>>>(q, k, v, f, m, qbuf, kbuf, vbuf, mwbuf);
  attn_main<<<2048, THREADS, 0, stream>>>(qbuf, kbuf, vbuf, mwbuf, out_o, out_attn);
}

// Round 3
// 150.798 us; speedup vs baseline: 1.1688x; 1.1688x over previous
//
#include <hip/hip_runtime.h>
#include <hip/hip_bf16.h>

#define S_ 1024
#define D_ 64
#define QBLK 32
#define THREADS 256

typedef __attribute__((ext_vector_type(8)))  short short8;
typedef __attribute__((ext_vector_type(4)))  int   int4v;
typedef __attribute__((ext_vector_type(16))) float f32x16;
typedef __attribute__((ext_vector_type(4)))  float f32x4;

__device__ __forceinline__ unsigned short f2bfu(float x) {
  return __builtin_bit_cast(unsigned short, __float2bfloat16(x));
}

// ---------------------------------------------------------------------------
// prep, grid ranges:
//  [0,2048)      qb = bf16(q * factor/8)                (8 elems/thread)
//  [2048,4096)   kb = bf16(k)
//  [4096,5120)   vp = bf16 V transposed+MFMA-permuted, via LDS tile:
//                vp[bh][d][C*16+hi*8+i] = V[bh][C*16+(i&3)+8*(i>>2)+4*hi][d]
//  [5120,21504)  mw bit-pack via wave ballot (coalesced)
// ---------------------------------------------------------------------------
__global__ __launch_bounds__(THREADS) void prep(
    const float* __restrict__ q, const float* __restrict__ k,
    const float* __restrict__ v, const float* __restrict__ factor,
    const int* __restrict__ mask, short* __restrict__ qb,
    short* __restrict__ kb, short* __restrict__ vp,
    unsigned* __restrict__ mw) {
  const int blk = blockIdx.x;
  const int tid = threadIdx.x;
  if (blk < 4096) {
    const bool isq = blk < 2048;
    const int gid = (isq ? blk : blk - 2048) * THREADS + tid;
    const int row = gid >> 3;                 // bh*S + s
    const int c8 = (gid & 7) << 3;
    const float fs = isq ? factor[row] * 0.125f : 1.0f;
    const float* src = (isq ? q : k) + (((size_t)row) << 6) + c8;
    f32x4 x0 = *(const f32x4*)src;
    f32x4 x1 = *(const f32x4*)(src + 4);
    short8 o;
#pragma unroll
    for (int i = 0; i < 4; ++i) {
      o[i] = (short)f2bfu(x0[i] * fs);
      o[i + 4] = (short)f2bfu(x1[i] * fs);
    }
    *(short8*)((isq ? qb : kb) + (((size_t)row) << 6) + c8) = o;
  } else if (blk < 5120) {
    __shared__ short vt[64 * 65];             // [klocal][d], stride 65
    const int g = blk - 4096;                 // bh*16 + kchunk
    const int bh = g >> 4;
    const int k0 = (g & 15) << 6;
    // load 64 keys x 64 d, coalesced
    const int kl = tid >> 2;
    const int d0 = (tid & 3) << 4;
    const float* vsrc = v + ((((size_t)bh << 10) + k0 + kl) << 6) + d0;
#pragma unroll
    for (int c = 0; c < 4; ++c) {
      f32x4 x = *(const f32x4*)(vsrc + 4 * c);
      short* dst = &vt[kl * 65 + d0 + 4 * c];
#pragma unroll
      for (int i = 0; i < 4; ++i) dst[i] = (short)f2bfu(x[i]);
    }
    __syncthreads();
    // write transposed+permuted, coalesced 32B/thread
    const int d = tid >> 2;
    const int g2 = tid & 3;
    short8 w0, w1;
#pragma unroll
    for (int i = 0; i < 8; ++i) {
      const int klo = (g2 << 4) + (i & 3) + ((i >> 2) << 3);
      w0[i] = vt[klo * 65 + d];               // hi = 0
      w1[i] = vt[(klo + 4) * 65 + d];         // hi = 1
    }
    short* dst = vp + ((size_t)bh << 16) + ((size_t)d << 10) + k0 + (g2 << 4);
    *(short8*)dst = w0;
    *(short8*)(dst + 8) = w1;
  } else {
    const int g = blk - 5120;
    const size_t base = (size_t)g * THREADS + tid;    // mask int index
    const unsigned long long bal = __ballot(mask[base] != 0);
    if ((tid & 63) == 0) {
      const size_t w2 = base >> 5;
      mw[w2] = (unsigned)bal;
      mw[w2 + 1] = (unsigned)(bal >> 32);
    }
  }
}

// ---------------------------------------------------------------------------
// A: swapped QK^T (lane = q-row) -> mask -> exp -> psum + PV with P lane-local
//    -> O (cross-wave LDS reduce) and inv_l to global.
// ---------------------------------------------------------------------------
__global__ __launch_bounds__(THREADS, 3) void attn_sums(
    const short* __restrict__ qb, const short* __restrict__ kb,
    const short* __restrict__ vp, const unsigned* __restrict__ mw,
    float* __restrict__ out_o, float* __restrict__ linv) {
  __shared__ float o_part[4][QBLK][D_];   // 32 KB
  __shared__ float rs[4][QBLK];
  __shared__ float inv_l[QBLK];

  const int tid = threadIdx.x;
  const int wave = tid >> 6;
  const int lane = tid & 63;
  const int hi = lane >> 5;
  const int ln = lane & 31;

  const int qt = blockIdx.x & 31;
  const int bh = blockIdx.x >> 5;
  const int b  = bh >> 4;
  const int q0 = qt * QBLK;

  const short* qp = qb + (((size_t)bh * S_ + q0) << 6);
  const short* kp = kb + ((size_t)bh << 16);
  const short* vpp = vp + ((size_t)bh << 16);
  const unsigned* mwb = mw + ((size_t)b << 15);

  short8 qf[4];
#pragma unroll
  for (int kc = 0; kc < 4; ++kc)
    qf[kc] = *(const short8*)(qp + (ln << 6) + (kc << 4) + (hi << 3));

  f32x16 oa0, oa1;
#pragma unroll
  for (int i = 0; i < 16; ++i) { oa0[i] = 0.f; oa1[i] = 0.f; }
  float psum = 0.f;

  for (int t = wave; t < 32; t += 4) {
    const int kv0 = t << 5;
    short8 kf[4];
#pragma unroll
    for (int kc = 0; kc < 4; ++kc)
      kf[kc] = *(const short8*)(kp + ((size_t)(kv0 + ln) << 6) + (kc << 4) + (hi << 3));
    f32x16 sB;
#pragma unroll
    for (int i = 0; i < 16; ++i) sB[i] = 0.f;
#pragma unroll
    for (int kc = 0; kc < 4; ++kc)
      sB = __builtin_amdgcn_mfma_f32_32x32x16_bf16(kf[kc], qf[kc], sB, 0, 0, 0);
    const unsigned wb = mwb[((q0 + ln) << 5) + t];
    int pk[8];
#pragma unroll
    for (int j = 0; j < 8; ++j) {
      const int r0 = 2 * j;
      const int k0 = (r0 & 3) + ((r0 >> 2) << 3) + (hi << 2);
      const float p0 = ((wb >> k0) & 1u) ? __expf(sB[r0]) : 0.f;
      const float p1 = ((wb >> (k0 + 1)) & 1u) ? __expf(sB[r0 + 1]) : 0.f;
      psum += p0 + p1;
      pk[j] = (int)f2bfu(p0) | ((int)f2bfu(p1) << 16);
    }
    int4v lo4 = {pk[0], pk[1], pk[2], pk[3]};
    int4v hi4 = {pk[4], pk[5], pk[6], pk[7]};
    const short8 pa0 = __builtin_bit_cast(short8, lo4);
    const short8 pa1 = __builtin_bit_cast(short8, hi4);
    const short* vr0 = vpp + ((size_t)ln << 10) + (t << 5) + (hi << 3);
    const short8 v00 = *(const short8*)(vr0);
    const short8 v01 = *(const short8*)(vr0 + 16);
    oa0 = __builtin_amdgcn_mfma_f32_32x32x16_bf16(pa0, v00, oa0, 0, 0, 0);
    oa0 = __builtin_amdgcn_mfma_f32_32x32x16_bf16(pa1, v01, oa0, 0, 0, 0);
    const short* vr1 = vr0 + (32 << 10);
    const short8 v10 = *(const short8*)(vr1);
    const short8 v11 = *(const short8*)(vr1 + 16);
    oa1 = __builtin_amdgcn_mfma_f32_32x32x16_bf16(pa0, v10, oa1, 0, 0, 0);
    oa1 = __builtin_amdgcn_mfma_f32_32x32x16_bf16(pa1, v11, oa1, 0, 0, 0);
  }

  psum += __shfl_xor(psum, 32);
  if (lane < 32) rs[wave][ln] = psum;
  __syncthreads();
  if (tid < QBLK) {
    const float il = 1.0f / (rs[0][tid] + rs[1][tid] + rs[2][tid] + rs[3][tid]);
    inv_l[tid] = il;
    linv[(size_t)bh * S_ + q0 + tid] = il;
  }

#pragma unroll
  for (int r = 0; r < 16; ++r) {
    const int row = (r & 3) + ((r >> 2) << 3) + (hi << 2);
    o_part[wave][row][ln] = oa0[r];
    o_part[wave][row][ln + 32] = oa1[r];
  }
  __syncthreads();
  float* op = out_o + (((size_t)bh * S_ + q0) << 6);
#pragma unroll
  for (int it = 0; it < 8; ++it) {
    const int idx = it * THREADS + tid;
    const int row = idx >> 6;
    const float o = o_part[0][row][idx & 63] + o_part[1][row][idx & 63] +
                    o_part[2][row][idx & 63] + o_part[3][row][idx & 63];
    op[idx] = o * inv_l[row];
  }
}

// ---------------------------------------------------------------------------
// B: lean attn-write streamer. Normal-orientation S = mfma(Q,K) (col = key),
//    mask words from 4KB LDS stage (broadcast), p = exp(S)*inv_l, nontemporal
//    scalar stores (two 128B segments per inst).
// ---------------------------------------------------------------------------
__global__ __launch_bounds__(THREADS, 5) void attn_write(
    const short* __restrict__ qb, const short* __restrict__ kb,
    const unsigned* __restrict__ mw, const float* __restrict__ linv,
    float* __restrict__ out_attn) {
  __shared__ unsigned lds_mw[QBLK * 32];   // 4 KB

  const int tid = threadIdx.x;
  const int wave = tid >> 6;
  const int lane = tid & 63;
  const int hi = lane >> 5;
  const int ln = lane & 31;

  const int qt = blockIdx.x & 31;
  const int bh = blockIdx.x >> 5;
  const int b  = bh >> 4;
  const int q0 = qt * QBLK;

  const unsigned* mwb = mw + ((size_t)b << 15) + ((size_t)q0 << 5);
#pragma unroll
  for (int i = tid; i < QBLK * 32; i += THREADS) lds_mw[i] = mwb[i];

  const short* qp = qb + (((size_t)bh * S_ + q0) << 6);
  const short* kp = kb + ((size_t)bh << 16);
  short8 qf[4];
#pragma unroll
  for (int kc = 0; kc < 4; ++kc)
    qf[kc] = *(const short8*)(qp + (ln << 6) + (kc << 4) + (hi << 3));

  const float* lp = linv + (size_t)bh * S_ + q0;
  f32x4 ilv[4];
#pragma unroll
  for (int g = 0; g < 4; ++g)
    ilv[g] = *(const f32x4*)(lp + (g << 3) + (hi << 2));

  __syncthreads();

  float* ap = out_attn + ((size_t)bh << 20) + ((size_t)q0 << 10);
  for (int t = wave; t < 32; t += 4) {
    short8 kf[4];
#pragma unroll
    for (int kc = 0; kc < 4; ++kc)
      kf[kc] = *(const short8*)(kp + ((size_t)((t << 5) + ln) << 6) + (kc << 4) + (hi << 3));
    f32x16 sA;
#pragma unroll
    for (int i = 0; i < 16; ++i) sA[i] = 0.f;
#pragma unroll
    for (int kc = 0; kc < 4; ++kc)
      sA = __builtin_amdgcn_mfma_f32_32x32x16_bf16(qf[kc], kf[kc], sA, 0, 0, 0);
#pragma unroll
    for (int r = 0; r < 16; ++r) {
      const int row = (r & 3) + ((r >> 2) << 3) + (hi << 2);
      const unsigned w = lds_mw[(row << 5) + t];
      const float il = ilv[r >> 2][r & 3];
      const float p = ((w >> ln) & 1u) ? __expf(sA[r]) * il : 0.f;
      __builtin_nontemporal_store(p, ap + ((size_t)row << 10) + (t << 5) + ln);
    }
  }
}

extern "C" void kernel_launch(void* const* d_in, const int* in_sizes, int n_in,
                              void* d_out, int out_size, void* d_ws, size_t ws_size,
                              hipStream_t stream) {
  (void)in_sizes; (void)n_in; (void)ws_size; (void)out_size;
  const float* q = (const float*)d_in[0];
  const float* k = (const float*)d_in[1];
  const float* v = (const float*)d_in[2];
  const float* f = (const float*)d_in[3];
  const int*   m = (const int*)d_in[4];
  float* out_o    = (float*)d_out;
  float* out_attn = out_o + (size_t)4 * 16 * 1024 * 64;

  short* qbuf = (short*)d_ws;                       // 8 MB
  short* kbuf = qbuf + 4194304;                     // 8 MB
  short* vbuf = kbuf + 4194304;                     // 8 MB
  unsigned* mwbuf = (unsigned*)(vbuf + 4194304);    // 512 KB
  float* linv = (float*)(mwbuf + 131072);           // 1 MB

  prep<<<21504, THREADS, 0, stream>>>(q, k, v, f, m, qbuf, kbuf, vbuf, mwbuf);
  attn_sums<<<2048, THREADS, 0, stream>>>(qbuf, kbuf, vbuf, mwbuf, out_o, linv);
  attn_write<<<2048, THREADS, 0, stream>>>(qbuf, kbuf, mwbuf, linv, out_attn);
}

// Round 4
// 129.864 us; speedup vs baseline: 1.3572x; 1.1612x over previous
//
#include <hip/hip_runtime.h>
#include <hip/hip_bf16.h>

#define S_ 1024
#define D_ 64
#define QBLK 32
#define THREADS 256

typedef __attribute__((ext_vector_type(8)))  short short8;
typedef __attribute__((ext_vector_type(4)))  int   int4v;
typedef __attribute__((ext_vector_type(16))) float f32x16;
typedef __attribute__((ext_vector_type(4)))  float f32x4;

__device__ __forceinline__ unsigned short f2bfu(float x) {
  return __builtin_bit_cast(unsigned short, __float2bfloat16(x));
}

// ---------------------------------------------------------------------------
// prep (unchanged from round 3):
//  [0,2048)      qb = bf16(q * factor/8)
//  [2048,4096)   kb = bf16(k)
//  [4096,5120)   vp = bf16 V transposed+MFMA-permuted via padded LDS tile
//  [5120,21504)  mw bit-pack via wave ballot
// ---------------------------------------------------------------------------
__global__ __launch_bounds__(THREADS) void prep(
    const float* __restrict__ q, const float* __restrict__ k,
    const float* __restrict__ v, const float* __restrict__ factor,
    const int* __restrict__ mask, short* __restrict__ qb,
    short* __restrict__ kb, short* __restrict__ vp,
    unsigned* __restrict__ mw) {
  const int blk = blockIdx.x;
  const int tid = threadIdx.x;
  if (blk < 4096) {
    const bool isq = blk < 2048;
    const int gid = (isq ? blk : blk - 2048) * THREADS + tid;
    const int row = gid >> 3;
    const int c8 = (gid & 7) << 3;
    const float fs = isq ? factor[row] * 0.125f : 1.0f;
    const float* src = (isq ? q : k) + (((size_t)row) << 6) + c8;
    f32x4 x0 = *(const f32x4*)src;
    f32x4 x1 = *(const f32x4*)(src + 4);
    short8 o;
#pragma unroll
    for (int i = 0; i < 4; ++i) {
      o[i] = (short)f2bfu(x0[i] * fs);
      o[i + 4] = (short)f2bfu(x1[i] * fs);
    }
    *(short8*)((isq ? qb : kb) + (((size_t)row) << 6) + c8) = o;
  } else if (blk < 5120) {
    __shared__ short vt[64 * 65];
    const int g = blk - 4096;
    const int bh = g >> 4;
    const int k0 = (g & 15) << 6;
    const int kl = tid >> 2;
    const int d0 = (tid & 3) << 4;
    const float* vsrc = v + ((((size_t)bh << 10) + k0 + kl) << 6) + d0;
#pragma unroll
    for (int c = 0; c < 4; ++c) {
      f32x4 x = *(const f32x4*)(vsrc + 4 * c);
      short* dst = &vt[kl * 65 + d0 + 4 * c];
#pragma unroll
      for (int i = 0; i < 4; ++i) dst[i] = (short)f2bfu(x[i]);
    }
    __syncthreads();
    const int d = tid >> 2;
    const int g2 = tid & 3;
    short8 w0, w1;
#pragma unroll
    for (int i = 0; i < 8; ++i) {
      const int klo = (g2 << 4) + (i & 3) + ((i >> 2) << 3);
      w0[i] = vt[klo * 65 + d];
      w1[i] = vt[(klo + 4) * 65 + d];
    }
    short* dst = vp + ((size_t)bh << 16) + ((size_t)d << 10) + k0 + (g2 << 4);
    *(short8*)dst = w0;
    *(short8*)(dst + 8) = w1;
  } else {
    const int g = blk - 5120;
    const size_t base = (size_t)g * THREADS + tid;
    const unsigned long long bal = __ballot(mask[base] != 0);
    if ((tid & 63) == 0) {
      const size_t w2 = base >> 5;
      mw[w2] = (unsigned)bal;
      mw[w2 + 1] = (unsigned)(bal >> 32);
    }
  }
}

// ---------------------------------------------------------------------------
// Merged main kernel. Block = (bh, 32 q-rows), XCD-swizzled so each XCD works
// on 8 consecutive bh (K/V working set 2MB < 4MB L2).
// Pass 1: swapped QK^T (lane = q-row) -> mask(LDS) -> exp -> psum + PV
//         (P lane-local, Vp fragments contiguous) -> inv_l, O.
// Pass 2: normal QK^T (L1/L2-hot K), exp * inv_l, nontemporal coalesced
//         stores of normalized attn straight from registers.
// ---------------------------------------------------------------------------
__global__ __launch_bounds__(THREADS, 3) void attn_fused2(
    const short* __restrict__ qb, const short* __restrict__ kb,
    const short* __restrict__ vp, const unsigned* __restrict__ mw,
    float* __restrict__ out_o, float* __restrict__ out_attn) {
  __shared__ float o_part[4][QBLK][D_];    // 32 KB
  __shared__ float rs[4][QBLK];
  __shared__ float inv_l[QBLK];
  __shared__ unsigned lds_mw[QBLK * 33];   // padded: avoids 32-way conflict

  const int tid = threadIdx.x;
  const int wave = tid >> 6;
  const int lane = tid & 63;
  const int hi = lane >> 5;
  const int ln = lane & 31;

  const int blk = blockIdx.x;
  const int swz = ((blk & 7) << 8) | (blk >> 3);   // XCD-contiguous bh
  const int qt = swz & 31;
  const int bh = swz >> 5;
  const int b  = bh >> 4;
  const int q0 = qt << 5;

  const short* qp = qb + (((size_t)bh * S_ + q0) << 6);
  const short* kp = kb + ((size_t)bh << 16);
  const short* vpp = vp + ((size_t)bh << 16);

  // stage mask words for this q-tile: rows q0..q0+31, 32 words each
  const unsigned* mwb = mw + ((size_t)b << 15) + ((size_t)q0 << 5);
#pragma unroll
  for (int i = tid; i < QBLK * 32; i += THREADS)
    lds_mw[(i >> 5) * 33 + (i & 31)] = mwb[i];

  short8 qf[4];
#pragma unroll
  for (int kc = 0; kc < 4; ++kc)
    qf[kc] = *(const short8*)(qp + (ln << 6) + (kc << 4) + (hi << 3));

  __syncthreads();

  f32x16 oa0, oa1;
#pragma unroll
  for (int i = 0; i < 16; ++i) { oa0[i] = 0.f; oa1[i] = 0.f; }
  float psum = 0.f;

  // ---- pass 1 ----
  for (int t = wave; t < 32; t += 4) {
    const int kv0 = t << 5;
    // issue ALL global loads first: they overlap the MFMA+exp chain
    const short* vr0 = vpp + ((size_t)ln << 10) + (t << 5) + (hi << 3);
    const short8 v00 = *(const short8*)(vr0);
    const short8 v01 = *(const short8*)(vr0 + 16);
    const short* vr1 = vr0 + (32 << 10);
    const short8 v10 = *(const short8*)(vr1);
    const short8 v11 = *(const short8*)(vr1 + 16);
    short8 kf[4];
#pragma unroll
    for (int kc = 0; kc < 4; ++kc)
      kf[kc] = *(const short8*)(kp + ((size_t)(kv0 + ln) << 6) + (kc << 4) + (hi << 3));
    f32x16 sB;
#pragma unroll
    for (int i = 0; i < 16; ++i) sB[i] = 0.f;
#pragma unroll
    for (int kc = 0; kc < 4; ++kc)
      sB = __builtin_amdgcn_mfma_f32_32x32x16_bf16(kf[kc], qf[kc], sB, 0, 0, 0);
    const unsigned wb = lds_mw[ln * 33 + t];
    int pk[8];
#pragma unroll
    for (int j = 0; j < 8; ++j) {
      const int r0 = 2 * j;
      const int k0 = (r0 & 3) + ((r0 >> 2) << 3) + (hi << 2);
      const float p0 = ((wb >> k0) & 1u) ? __expf(sB[r0]) : 0.f;
      const float p1 = ((wb >> (k0 + 1)) & 1u) ? __expf(sB[r0 + 1]) : 0.f;
      psum += p0 + p1;
      pk[j] = (int)f2bfu(p0) | ((int)f2bfu(p1) << 16);
    }
    int4v lo4 = {pk[0], pk[1], pk[2], pk[3]};
    int4v hi4 = {pk[4], pk[5], pk[6], pk[7]};
    const short8 pa0 = __builtin_bit_cast(short8, lo4);
    const short8 pa1 = __builtin_bit_cast(short8, hi4);
    oa0 = __builtin_amdgcn_mfma_f32_32x32x16_bf16(pa0, v00, oa0, 0, 0, 0);
    oa0 = __builtin_amdgcn_mfma_f32_32x32x16_bf16(pa1, v01, oa0, 0, 0, 0);
    oa1 = __builtin_amdgcn_mfma_f32_32x32x16_bf16(pa0, v10, oa1, 0, 0, 0);
    oa1 = __builtin_amdgcn_mfma_f32_32x32x16_bf16(pa1, v11, oa1, 0, 0, 0);
  }

  // ---- row sums -> inv_l ----
  psum += __shfl_xor(psum, 32);
  if (lane < 32) rs[wave][ln] = psum;
  __syncthreads();
  if (tid < QBLK)
    inv_l[tid] = 1.0f / (rs[0][tid] + rs[1][tid] + rs[2][tid] + rs[3][tid]);

  // ---- O cross-wave reduce ----
#pragma unroll
  for (int r = 0; r < 16; ++r) {
    const int row = (r & 3) + ((r >> 2) << 3) + (hi << 2);
    o_part[wave][row][ln] = oa0[r];
    o_part[wave][row][ln + 32] = oa1[r];
  }
  __syncthreads();

  f32x4 ilv[4];
#pragma unroll
  for (int g = 0; g < 4; ++g)
    ilv[g] = *(const f32x4*)&inv_l[(g << 3) + (hi << 2)];

  float* op = out_o + (((size_t)bh * S_ + q0) << 6);
#pragma unroll
  for (int it = 0; it < 8; ++it) {
    const int idx = it * THREADS + tid;
    const int row = idx >> 6;
    const float o = o_part[0][row][idx & 63] + o_part[1][row][idx & 63] +
                    o_part[2][row][idx & 63] + o_part[3][row][idx & 63];
    op[idx] = o * inv_l[row];
  }

  // ---- pass 2: recompute S (K is cache-hot), stream normalized attn ----
  float* ap = out_attn + ((size_t)bh << 20) + ((size_t)q0 << 10);
  for (int t = wave; t < 32; t += 4) {
    short8 kf[4];
#pragma unroll
    for (int kc = 0; kc < 4; ++kc)
      kf[kc] = *(const short8*)(kp + ((size_t)((t << 5) + ln) << 6) + (kc << 4) + (hi << 3));
    f32x16 sA;
#pragma unroll
    for (int i = 0; i < 16; ++i) sA[i] = 0.f;
#pragma unroll
    for (int kc = 0; kc < 4; ++kc)
      sA = __builtin_amdgcn_mfma_f32_32x32x16_bf16(qf[kc], kf[kc], sA, 0, 0, 0);
#pragma unroll
    for (int r = 0; r < 16; ++r) {
      const int row = (r & 3) + ((r >> 2) << 3) + (hi << 2);
      const unsigned w = lds_mw[row * 33 + t];
      const float il = ilv[r >> 2][r & 3];
      const float p = ((w >> ln) & 1u) ? __expf(sA[r]) * il : 0.f;
      __builtin_nontemporal_store(p, ap + ((size_t)row << 10) + (t << 5) + ln);
    }
  }
}

extern "C" void kernel_launch(void* const* d_in, const int* in_sizes, int n_in,
                              void* d_out, int out_size, void* d_ws, size_t ws_size,
                              hipStream_t stream) {
  (void)in_sizes; (void)n_in; (void)ws_size; (void)out_size;
  const float* q = (const float*)d_in[0];
  const float* k = (const float*)d_in[1];
  const float* v = (const float*)d_in[2];
  const float* f = (const float*)d_in[3];
  const int*   m = (const int*)d_in[4];
  float* out_o    = (float*)d_out;
  float* out_attn = out_o + (size_t)4 * 16 * 1024 * 64;

  short* qbuf = (short*)d_ws;                       // 8 MB
  short* kbuf = qbuf + 4194304;                     // 8 MB
  short* vbuf = kbuf + 4194304;                     // 8 MB
  unsigned* mwbuf = (unsigned*)(vbuf + 4194304);    // 512 KB

  prep<<<21504, THREADS, 0, stream>>>(q, k, v, f, m, qbuf, kbuf, vbuf, mwbuf);
  attn_fused2<<<2048, THREADS, 0, stream>>>(qbuf, kbuf, vbuf, mwbuf, out_o, out_attn);
}

// Round 5
// 128.693 us; speedup vs baseline: 1.3696x; 1.0091x over previous
//
#include <hip/hip_runtime.h>
#include <hip/hip_bf16.h>

#define S_ 1024
#define D_ 64
#define QBLK 32
#define THREADS 256
#define LOG2E 1.44269504088896f

typedef __attribute__((ext_vector_type(8)))  short short8;
typedef __attribute__((ext_vector_type(4)))  int   int4v;
typedef __attribute__((ext_vector_type(16))) float f32x16;
typedef __attribute__((ext_vector_type(4)))  float f32x4;

__device__ __forceinline__ unsigned short f2bfu(float x) {
  return __builtin_bit_cast(unsigned short, __float2bfloat16(x));
}

// ---------------------------------------------------------------------------
// prep:
//  [0,2048)     kb = bf16(k)                       (8 elems/thread)
//  [2048,3072)  vp = bf16 V transposed+MFMA-permuted via padded LDS tile
//  [3072,5120)  mw bit-pack via wave ballot, grid-strided x8
// (q is NOT pre-converted: main reads f32 q once into registers.)
// ---------------------------------------------------------------------------
__global__ __launch_bounds__(THREADS) void prep(
    const float* __restrict__ k, const float* __restrict__ v,
    const int* __restrict__ mask, short* __restrict__ kb,
    short* __restrict__ vp, unsigned* __restrict__ mw) {
  const int blk = blockIdx.x;
  const int tid = threadIdx.x;
  if (blk < 2048) {
    const int gid = blk * THREADS + tid;
    const int row = gid >> 3;
    const int c8 = (gid & 7) << 3;
    const float* src = k + (((size_t)row) << 6) + c8;
    f32x4 x0 = *(const f32x4*)src;
    f32x4 x1 = *(const f32x4*)(src + 4);
    short8 o;
#pragma unroll
    for (int i = 0; i < 4; ++i) {
      o[i] = (short)f2bfu(x0[i]);
      o[i + 4] = (short)f2bfu(x1[i]);
    }
    *(short8*)(kb + (((size_t)row) << 6) + c8) = o;
  } else if (blk < 3072) {
    __shared__ short vt[64 * 65];
    const int g = blk - 2048;                 // bh*16 + kchunk
    const int bh = g >> 4;
    const int k0 = (g & 15) << 6;
    const int kl = tid >> 2;
    const int d0 = (tid & 3) << 4;
    const float* vsrc = v + ((((size_t)bh << 10) + k0 + kl) << 6) + d0;
#pragma unroll
    for (int c = 0; c < 4; ++c) {
      f32x4 x = *(const f32x4*)(vsrc + 4 * c);
      short* dst = &vt[kl * 65 + d0 + 4 * c];
#pragma unroll
      for (int i = 0; i < 4; ++i) dst[i] = (short)f2bfu(x[i]);
    }
    __syncthreads();
    const int d = tid >> 2;
    const int g2 = tid & 3;
    short8 w0, w1;
#pragma unroll
    for (int i = 0; i < 8; ++i) {
      const int klo = (g2 << 4) + (i & 3) + ((i >> 2) << 3);
      w0[i] = vt[klo * 65 + d];
      w1[i] = vt[(klo + 4) * 65 + d];
    }
    short* dst = vp + ((size_t)bh << 16) + ((size_t)d << 10) + k0 + (g2 << 4);
    *(short8*)dst = w0;
    *(short8*)(dst + 8) = w1;
  } else {
    const int g = blk - 3072;                 // 0..2047, 8 ballots each
#pragma unroll
    for (int it = 0; it < 8; ++it) {
      const size_t base = ((size_t)g * 8 + it) * THREADS + tid;
      const unsigned long long bal = __ballot(mask[base] != 0);
      if ((tid & 63) == 0) {
        const size_t w2 = base >> 5;
        mw[w2] = (unsigned)bal;
        mw[w2 + 1] = (unsigned)(bal >> 32);
      }
    }
  }
}

// ---------------------------------------------------------------------------
// Main. Block = (bh, 32 q-rows), XCD-swizzled (8 consecutive bh per XCD).
// qf built from f32 q with factor/8*log2e folded in; exp via v_exp_f32 (2^x).
// Pass 1: swapped QK^T -> mask(LDS) -> exp2 -> psum + PV (Vp contiguous).
// inv_l; O reduced in two 16KB LDS stages (d0-31, d32-63).
// Pass 2: normal QK^T (K cache-hot), exp2 * inv_l, nontemporal stores.
// ---------------------------------------------------------------------------
__global__ __launch_bounds__(THREADS, 4) void attn_main(
    const float* __restrict__ q, const float* __restrict__ factor,
    const short* __restrict__ kb, const short* __restrict__ vp,
    const unsigned* __restrict__ mw, float* __restrict__ out_o,
    float* __restrict__ out_attn) {
  __shared__ float o_red[4][QBLK][32];     // 16 KB, reused for both d-halves
  __shared__ unsigned lds_mw[QBLK * 33];   // 4.2 KB, padded
  __shared__ float rs[4][QBLK];
  __shared__ float inv_l[QBLK];

  const int tid = threadIdx.x;
  const int wave = tid >> 6;
  const int lane = tid & 63;
  const int hi = lane >> 5;
  const int ln = lane & 31;

  const int blk = blockIdx.x;
  const int swz = ((blk & 7) << 8) | (blk >> 3);   // XCD-contiguous bh
  const int qt = swz & 31;
  const int bh = swz >> 5;
  const int b  = bh >> 4;
  const int q0 = qt << 5;

  const short* kp = kb + ((size_t)bh << 16);
  const short* vpp = vp + ((size_t)bh << 16);

  const unsigned* mwb = mw + ((size_t)b << 15) + ((size_t)q0 << 5);
#pragma unroll
  for (int i = tid; i < QBLK * 32; i += THREADS)
    lds_mw[(i >> 5) * 33 + (i & 31)] = mwb[i];

  // qf from f32 q, scaled by factor/8 * log2e
  const size_t qrow = (size_t)bh * S_ + q0 + ln;
  const float fs = factor[qrow] * 0.125f * LOG2E;
  const float* qsrc = q + (qrow << 6) + (hi << 3);
  short8 qf[4];
#pragma unroll
  for (int kc = 0; kc < 4; ++kc) {
    f32x4 x0 = *(const f32x4*)(qsrc + (kc << 4));
    f32x4 x1 = *(const f32x4*)(qsrc + (kc << 4) + 4);
    short8 a;
#pragma unroll
    for (int i = 0; i < 4; ++i) { a[i] = (short)f2bfu(x0[i] * fs); a[i + 4] = (short)f2bfu(x1[i] * fs); }
    qf[kc] = a;
  }

  __syncthreads();

  f32x16 oa0, oa1;
#pragma unroll
  for (int i = 0; i < 16; ++i) { oa0[i] = 0.f; oa1[i] = 0.f; }
  float psum = 0.f;

  // ---- pass 1: swapped QK^T + PV ----
  for (int t = wave; t < 32; t += 4) {
    short8 kf[4];
#pragma unroll
    for (int kc = 0; kc < 4; ++kc)
      kf[kc] = *(const short8*)(kp + ((size_t)((t << 5) + ln) << 6) + (kc << 4) + (hi << 3));
    f32x16 sB;
#pragma unroll
    for (int i = 0; i < 16; ++i) sB[i] = 0.f;
#pragma unroll
    for (int kc = 0; kc < 4; ++kc)
      sB = __builtin_amdgcn_mfma_f32_32x32x16_bf16(kf[kc], qf[kc], sB, 0, 0, 0);
    const unsigned wb = lds_mw[ln * 33 + t];
    int pk[8];
#pragma unroll
    for (int j = 0; j < 8; ++j) {
      const int r0 = 2 * j;
      const int k0 = (r0 & 3) + ((r0 >> 2) << 3) + (hi << 2);
      const float p0 = ((wb >> k0) & 1u) ? __builtin_amdgcn_exp2f(sB[r0]) : 0.f;
      const float p1 = ((wb >> (k0 + 1)) & 1u) ? __builtin_amdgcn_exp2f(sB[r0 + 1]) : 0.f;
      psum += p0 + p1;
      pk[j] = (int)f2bfu(p0) | ((int)f2bfu(p1) << 16);
    }
    int4v lo4 = {pk[0], pk[1], pk[2], pk[3]};
    int4v hi4 = {pk[4], pk[5], pk[6], pk[7]};
    const short8 pa0 = __builtin_bit_cast(short8, lo4);
    const short8 pa1 = __builtin_bit_cast(short8, hi4);
    // V fragments loaded late to keep pass-1 peak register set small
    const short* vr0 = vpp + ((size_t)ln << 10) + (t << 5) + (hi << 3);
    const short8 v00 = *(const short8*)(vr0);
    const short8 v01 = *(const short8*)(vr0 + 16);
    oa0 = __builtin_amdgcn_mfma_f32_32x32x16_bf16(pa0, v00, oa0, 0, 0, 0);
    oa0 = __builtin_amdgcn_mfma_f32_32x32x16_bf16(pa1, v01, oa0, 0, 0, 0);
    const short* vr1 = vr0 + (32 << 10);
    const short8 v10 = *(const short8*)(vr1);
    const short8 v11 = *(const short8*)(vr1 + 16);
    oa1 = __builtin_amdgcn_mfma_f32_32x32x16_bf16(pa0, v10, oa1, 0, 0, 0);
    oa1 = __builtin_amdgcn_mfma_f32_32x32x16_bf16(pa1, v11, oa1, 0, 0, 0);
  }

  // ---- row sums -> inv_l ----
  psum += __shfl_xor(psum, 32);
  if (lane < 32) rs[wave][ln] = psum;
  __syncthreads();
  if (tid < QBLK)
    inv_l[tid] = 1.0f / (rs[0][tid] + rs[1][tid] + rs[2][tid] + rs[3][tid]);

  // ---- O reduce, stage A (d 0-31) ----
#pragma unroll
  for (int r = 0; r < 16; ++r) {
    const int row = (r & 3) + ((r >> 2) << 3) + (hi << 2);
    o_red[wave][row][ln] = oa0[r];
  }
  __syncthreads();   // covers inv_l + stage-A writes

  f32x4 ilv[4];
#pragma unroll
  for (int g = 0; g < 4; ++g)
    ilv[g] = *(const f32x4*)&inv_l[(g << 3) + (hi << 2)];

  float* op = out_o + (((size_t)bh * S_ + q0) << 6);
#pragma unroll
  for (int it = 0; it < 4; ++it) {
    const int idx = it * THREADS + tid;
    const int row = idx >> 5;
    const int d = idx & 31;
    const float o = o_red[0][row][d] + o_red[1][row][d] + o_red[2][row][d] + o_red[3][row][d];
    __builtin_nontemporal_store(o * inv_l[row], op + (row << 6) + d);
  }
  __syncthreads();

  // ---- O reduce, stage B (d 32-63) ----
#pragma unroll
  for (int r = 0; r < 16; ++r) {
    const int row = (r & 3) + ((r >> 2) << 3) + (hi << 2);
    o_red[wave][row][ln] = oa1[r];
  }
  __syncthreads();
#pragma unroll
  for (int it = 0; it < 4; ++it) {
    const int idx = it * THREADS + tid;
    const int row = idx >> 5;
    const int d = idx & 31;
    const float o = o_red[0][row][d] + o_red[1][row][d] + o_red[2][row][d] + o_red[3][row][d];
    __builtin_nontemporal_store(o * inv_l[row], op + (row << 6) + 32 + d);
  }

  // ---- pass 2: recompute S (K cache-hot), stream normalized attn ----
  float* ap = out_attn + ((size_t)bh << 20) + ((size_t)q0 << 10);
  for (int t = wave; t < 32; t += 4) {
    short8 kf[4];
#pragma unroll
    for (int kc = 0; kc < 4; ++kc)
      kf[kc] = *(const short8*)(kp + ((size_t)((t << 5) + ln) << 6) + (kc << 4) + (hi << 3));
    f32x16 sA;
#pragma unroll
    for (int i = 0; i < 16; ++i) sA[i] = 0.f;
#pragma unroll
    for (int kc = 0; kc < 4; ++kc)
      sA = __builtin_amdgcn_mfma_f32_32x32x16_bf16(qf[kc], kf[kc], sA, 0, 0, 0);
#pragma unroll
    for (int r = 0; r < 16; ++r) {
      const int row = (r & 3) + ((r >> 2) << 3) + (hi << 2);
      const unsigned w = lds_mw[row * 33 + t];
      const float il = ilv[r >> 2][r & 3];
      const float p = ((w >> ln) & 1u) ? __builtin_amdgcn_exp2f(sA[r]) * il : 0.f;
      __builtin_nontemporal_store(p, ap + ((size_t)row << 10) + (t << 5) + ln);
    }
  }
}

extern "C" void kernel_launch(void* const* d_in, const int* in_sizes, int n_in,
                              void* d_out, int out_size, void* d_ws, size_t ws_size,
                              hipStream_t stream) {
  (void)in_sizes; (void)n_in; (void)ws_size; (void)out_size;
  const float* q = (const float*)d_in[0];
  const float* k = (const float*)d_in[1];
  const float* v = (const float*)d_in[2];
  const float* f = (const float*)d_in[3];
  const int*   m = (const int*)d_in[4];
  float* out_o    = (float*)d_out;
  float* out_attn = out_o + (size_t)4 * 16 * 1024 * 64;

  short* kbuf = (short*)d_ws;                       // 8 MB
  short* vbuf = kbuf + 4194304;                     // 8 MB
  unsigned* mwbuf = (unsigned*)(vbuf + 4194304);    // 512 KB

  prep<<<5120, THREADS, 0, stream>>>(k, v, m, kbuf, vbuf, mwbuf);
  attn_main<<<2048, THREADS, 0, stream>>>(q, f, kbuf, vbuf, mwbuf, out_o, out_attn);
}